// Round 8
// baseline (156.084 us; speedup 1.0000x reference)
//
#include <hip/hip_runtime.h>
#include <hip/hip_bf16.h>
#include <math.h>

#define Bsz 8
#define Hh 64
#define Ww 64
#define Cc 256
#define Nn 64
#define Ll 4096      /* Hh*Ww */
#define EPSf 1e-5f

typedef __bf16 v8bf __attribute__((ext_vector_type(8)));
typedef float  f32x4 __attribute__((ext_vector_type(4)));

__device__ __forceinline__ float ad_val(float a, float snr) {
    float s = fminf(fmaxf(snr, 0.f), 1.f);
    float scale = 0.6f + 0.4f * s;
    float v = tanhf(a) * scale;
    return fminf(fmaxf(v, -0.99f), 0.99f);
}

// K0: weights -> bf16 MFMA B-fragment order. W_in and Wo' (= Wout*0.25*Cp[k],
// exact pow2 scales) both stored as hi/lo bf16 splits. WB = rowsum(Win)*Bp.
__global__ __launch_bounds__(256) void k0_weights(
    const float* __restrict__ Win, const float* __restrict__ Wout,
    const float* __restrict__ Bp, const float* __restrict__ Cp,
    __bf16* __restrict__ Wh, __bf16* __restrict__ Wl,
    __bf16* __restrict__ Woh, __bf16* __restrict__ Wol,
    float* __restrict__ WB)
{
    const int t = threadIdx.x;
    const int blk = blockIdx.x;
    if (blk < 4) {
        for (int idx = blk * 512 + t; idx < blk * 512 + 512; idx += 256) {
            int tile = idx >> 6, lane = idx & 63;
            int kt = tile >> 2, nt = tile & 3;
            int q = lane >> 4, n = nt * 16 + (lane & 15);
            #pragma unroll
            for (int j = 0; j < 8; ++j) {
                int k = kt * 32 + q * 8 + j;
                float w = Win[n * Cc + k];
                __bf16 h = (__bf16)w;
                Wh[idx * 8 + j] = h;
                Wl[idx * 8 + j] = (__bf16)(w - (float)h);
            }
        }
    } else if (blk < 8) {
        for (int idx = (blk - 4) * 512 + t; idx < (blk - 4) * 512 + 512; idx += 256) {
            int tile = idx >> 6, lane = idx & 63;
            int kt = tile >> 4, ntg = tile & 15;
            int q = lane >> 4, c = ntg * 16 + (lane & 15);
            #pragma unroll
            for (int j = 0; j < 8; ++j) {
                int k = kt * 32 + q * 8 + j;
                float w = Wout[c * Nn + k] * 0.25f * Cp[k];
                __bf16 h = (__bf16)w;
                Woh[idx * 8 + j] = h;
                Wol[idx * 8 + j] = (__bf16)(w - (float)h);
            }
        }
    } else {
        __shared__ float wtmp[256];
        int n = t >> 2, qd = t & 3;
        float s = 0.f;
        const float* wr = Win + (long)n * Cc + qd * 64;
        for (int i = 0; i < 64; ++i) s += wr[i];
        wtmp[t] = s;
        __syncthreads();
        if (t < 64)
            WB[t] = (wtmp[t*4] + wtmp[t*4+1] + wtmp[t*4+2] + wtmp[t*4+3]) * Bp[t];
    }
}

// K1: LN stats + MFMA input projection on raw x (LN folded into epilogue):
//   Bu[p][n] = Bp[n]*s[p]*((x@Win^T)[p][n]) - s[p]*m[p]*WB[n].
// 512 blocks x 256 thr; 2-term bf16 split (xh*Wh + xl*Wh + xh*Wl). (R3-proven.)
__global__ __launch_bounds__(256) void k1_ln_gemm(
    const float* __restrict__ x, const __bf16* __restrict__ Wh,
    const __bf16* __restrict__ Wl, const float* __restrict__ Bp,
    const float* __restrict__ WB, float* __restrict__ Bu,
    float* __restrict__ Mst, float* __restrict__ Sst)
{
    __shared__ float mrow[64], srow[64];
    const int t = threadIdx.x;
    const int lane = t & 63;
    const int wv = __builtin_amdgcn_readfirstlane(t >> 6);
    const long pbase = (long)blockIdx.x * 64;
    const float* xt = x + pbase * Cc;

    for (int rr = 0; rr < 16; ++rr) {
        int r = wv * 16 + rr;
        float4 v = ((const float4*)(xt + (long)r * Cc))[lane];
        float s = v.x + v.y + v.z + v.w;
        float q = v.x*v.x + v.y*v.y + v.z*v.z + v.w*v.w;
        #pragma unroll
        for (int off = 32; off > 0; off >>= 1) {
            s += __shfl_down(s, off);
            q += __shfl_down(q, off);
        }
        if (lane == 0) {
            float m = s * (1.f/256.f);
            float var = fmaxf(q * (1.f/256.f) - m*m, 0.f);
            float r1 = rsqrtf(var + EPSf);
            float v2 = var / (var + EPSf);
            float sc = r1 * rsqrtf(v2 + EPSf);
            mrow[r] = m; srow[r] = sc;
            Mst[pbase + r] = m; Sst[pbase + r] = sc;
        }
    }
    __syncthreads();

    const int q = lane >> 4;
    const int mi = lane & 15;
    const float* xa = xt + (long)(wv * 16 + mi) * Cc + q * 8;

    f32x4 acc[4];
    #pragma unroll
    for (int nt = 0; nt < 4; ++nt) acc[nt] = (f32x4){0.f, 0.f, 0.f, 0.f};

    #pragma unroll
    for (int kt = 0; kt < 8; ++kt) {
        float4 a0 = *(const float4*)(xa + kt * 32);
        float4 a1 = *(const float4*)(xa + kt * 32 + 4);
        float av[8] = {a0.x, a0.y, a0.z, a0.w, a1.x, a1.y, a1.z, a1.w};
        v8bf ah, al;
        #pragma unroll
        for (int j = 0; j < 8; ++j) {
            __bf16 h = (__bf16)av[j];
            ah[j] = h;
            al[j] = (__bf16)(av[j] - (float)h);
        }
        #pragma unroll
        for (int nt = 0; nt < 4; ++nt) {
            v8bf bh = *(const v8bf*)(Wh + ((long)(kt * 4 + nt) * 64 + lane) * 8);
            v8bf bl = *(const v8bf*)(Wl + ((long)(kt * 4 + nt) * 64 + lane) * 8);
            acc[nt] = __builtin_amdgcn_mfma_f32_16x16x32_bf16(ah, bh, acc[nt], 0, 0, 0);
            acc[nt] = __builtin_amdgcn_mfma_f32_16x16x32_bf16(al, bh, acc[nt], 0, 0, 0);
            acc[nt] = __builtin_amdgcn_mfma_f32_16x16x32_bf16(ah, bl, acc[nt], 0, 0, 0);
        }
    }

    #pragma unroll
    for (int nt = 0; nt < 4; ++nt) {
        int n = nt * 16 + mi;
        float bpn = Bp[n];
        float wbn = WB[n];
        #pragma unroll
        for (int reg = 0; reg < 4; ++reg) {
            int p = wv * 16 + q * 4 + reg;
            float m = mrow[p], s = srow[p];
            Bu[(pbase + p) * Nn + n] = s * (acc[nt][reg] * bpn - m * wbn);
        }
    }
}

// K2: chunk carries. 512 blocks x 256 thr; TWO waves per chunk (32 elems each,
// composed via Ad^32) -> half-length chains, 2 blocks/CU. No reconstruction.
// Writes full-chunk local carries to E and half-partials (pf_lo, pb_hi) to P.
__global__ __launch_bounds__(256) void k2_carry(
    const float* __restrict__ Bu, const float* __restrict__ A,
    const float* __restrict__ snr, float* __restrict__ E,
    float* __restrict__ Pf, float* __restrict__ Pb)
{
    __shared__ float exch[2][2][64];
    const int t = threadIdx.x;
    const int lane = t & 63;
    const int wv = t >> 6;
    const int pairIdx = wv >> 1;        // 0,1: which task in this block
    const int half = wv & 1;            // 0 = elems 0..31, 1 = 32..63
    const int task = blockIdx.x * 2 + pairIdx;
    const int isCol = task >> 9;
    const int b = (task >> 6) & 7;
    const int j = task & 63;
    const float Ad = ad_val(A[lane], snr[b]);
    float p32 = Ad;
    #pragma unroll
    for (int i = 0; i < 5; ++i) p32 *= p32;        // Ad^32
    const long stride = isCol ? (long)Ww * Nn : Nn;
    const float* src = Bu + ((long)b * Ll + (isCol ? j : j * 64)) * Nn
                       + (long)half * 32 * stride + lane;
    float v[32];
    #pragma unroll
    for (int k = 0; k < 32; ++k) v[k] = src[k * stride];
    float pf = 0.f;                                 // local fwd partial
    #pragma unroll
    for (int k = 0; k < 32; ++k) pf = fmaf(Ad, pf, v[k]);
    float pb = 0.f;                                 // local bwd partial
    #pragma unroll
    for (int k = 31; k >= 0; --k) pb = fmaf(Ad, pb, v[k]);
    if (half) { exch[pairIdx][0][lane] = pf; exch[pairIdx][1][lane] = pb; }
    __syncthreads();
    if (!half) {
        const int dF = isCol ? 2 : 0;
        float pf_hi = exch[pairIdx][0][lane];
        float pb_hi = exch[pairIdx][1][lane];
        // E_f = Ad^32*pf_lo + pf_hi ; E_b = Ad^32*pb_hi + pb_lo
        E[((dF * 8 + b) * 64 + j) * 64 + lane]              = fmaf(p32, pf, pf_hi);
        E[(((dF + 1) * 8 + b) * 64 + (63 - j)) * 64 + lane] = fmaf(p32, pb_hi, pb);
        Pf[task * 64 + lane] = pf;                  // pf_lo (local)
        Pb[task * 64 + lane] = pb_hi;               // pb_hi (local)
    }
}

// K4: apply. 512 blocks x 256 thr, two waves per chunk. Each wave computes its
// own carry prefixes inline from E (Ad^64 composition; k3 eliminated), seeds
// its half with the Ad^32-composed partials from P, scans 32 elems, writes S.
__global__ __launch_bounds__(256) void k4_apply(
    const float* __restrict__ Bu, const float* __restrict__ E,
    const float* __restrict__ Pf, const float* __restrict__ Pb,
    const float* __restrict__ A, const float* __restrict__ snr,
    float* __restrict__ Srow, float* __restrict__ Scol)
{
    const int t = threadIdx.x;
    const int lane = t & 63;
    const int wv = t >> 6;
    const int task = blockIdx.x * 2 + (wv >> 1);
    const int half = wv & 1;
    const int isCol = task >> 9;
    const int b = (task >> 6) & 7;
    const int j = task & 63;
    const float Ad = ad_val(A[lane], snr[b]);
    float p32 = Ad;
    #pragma unroll
    for (int i = 0; i < 5; ++i) p32 *= p32;        // Ad^32
    float p64 = p32 * p32;                         // Ad^64
    const int dF = isCol ? 2 : 0;

    // inline exclusive carry prefixes (wave-uniform trip counts, L2-hot)
    const float* Ef = E + (long)((dF * 8 + b) * 64) * 64 + lane;
    const float* Eb = E + (long)(((dF + 1) * 8 + b) * 64) * 64 + lane;
    float cf = 0.f;
    #pragma unroll 4
    for (int i = 0; i < j; ++i) cf = fmaf(p64, cf, Ef[i * 64]);
    float cb = 0.f;
    const int jj = 63 - j;
    #pragma unroll 4
    for (int i = 0; i < jj; ++i) cb = fmaf(p64, cb, Eb[i * 64]);

    // seeds for this half
    float fseed = half ? fmaf(p32, cf, Pf[task * 64 + lane]) : cf;
    float bseed = half ? cb : fmaf(p32, cb, Pb[task * 64 + lane]);

    const long stride = isCol ? (long)Ww * Nn : Nn;
    const long base = ((long)b * Ll + (isCol ? j : j * 64)) * Nn
                      + (long)half * 32 * stride + lane;
    const float* src = Bu + base;
    float v[32];
    #pragma unroll
    for (int k = 0; k < 32; ++k) v[k] = src[k * stride];

    float hf[32];
    float h = fseed;
    #pragma unroll
    for (int k = 0; k < 32; ++k) { h = fmaf(Ad, h, v[k]); hf[k] = h; }

    float* out0 = (isCol ? Scol : Srow) + base;
    float sb = bseed;
    #pragma unroll
    for (int k = 31; k >= 0; --k) {
        sb = fmaf(Ad, sb, v[k]);
        out0[k * stride] = hf[k] + sb;
    }
}

// K5: MFMA output projection y = (Srow+Scol) @ Wo'^T + D*z (Wo' = 0.25*Cp
// folded). fp32 S staged+added in LDS; 3-term bf16 split GEMM; out-tile
// streamed through LDS in TWO 32-row passes (33.3 KB -> 4 blocks/CU).
__global__ __launch_bounds__(256) void k5_gemm_out(
    const float* __restrict__ Srow, const float* __restrict__ Scol,
    const float* __restrict__ x, const __bf16* __restrict__ Woh,
    const __bf16* __restrict__ Wol, const float* __restrict__ Dp,
    const float* __restrict__ Mst, const float* __restrict__ Sst,
    float* __restrict__ out)
{
    __shared__ float smem[32 * 260];    // S stage (64x68=4352 floats) fits too
    const int t = threadIdx.x;
    const int lane = t & 63;
    const int wv = __builtin_amdgcn_readfirstlane(t >> 6);
    const long pbase = (long)blockIdx.x * 64;
    const int q = lane >> 4;
    const int mi = lane & 15;

    // stage S = Srow + Scol (coalesced float4), 64 rows x 64 states, stride 68
    const float4* Sr = (const float4*)(Srow + pbase * Nn);
    const float4* Sc = (const float4*)(Scol + pbase * Nn);
    #pragma unroll
    for (int i = 0; i < 4; ++i) {
        int fi = i * 256 + t;           // p = fi>>4, n4 = fi&15
        float4 a = Sr[fi], c = Sc[fi];
        *(float4*)&smem[(fi >> 4) * 68 + (fi & 15) * 4] =
            make_float4(a.x + c.x, a.y + c.y, a.z + c.z, a.w + c.w);
    }
    __syncthreads();

    f32x4 acc[4][4];
    #pragma unroll
    for (int mt = 0; mt < 4; ++mt)
        #pragma unroll
        for (int nt = 0; nt < 4; ++nt) acc[mt][nt] = (f32x4){0.f, 0.f, 0.f, 0.f};

    #pragma unroll
    for (int kt = 0; kt < 2; ++kt) {
        v8bf bh[4], bl[4];
        #pragma unroll
        for (int nt = 0; nt < 4; ++nt) {
            long wo = ((long)(kt * 16 + wv * 4 + nt) * 64 + lane) * 8;
            bh[nt] = *(const v8bf*)(Woh + wo);
            bl[nt] = *(const v8bf*)(Wol + wo);
        }
        #pragma unroll
        for (int mt = 0; mt < 4; ++mt) {
            const float* ar = &smem[(mt * 16 + mi) * 68 + q * 8 + kt * 32];
            v8bf sh, sl;
            #pragma unroll
            for (int j = 0; j < 8; ++j) {
                float sv = ar[j];
                __bf16 hh = (__bf16)sv;
                sh[j] = hh;
                sl[j] = (__bf16)(sv - (float)hh);
            }
            #pragma unroll
            for (int nt = 0; nt < 4; ++nt) {
                acc[mt][nt] = __builtin_amdgcn_mfma_f32_16x16x32_bf16(sh, bh[nt], acc[mt][nt], 0, 0, 0);
                acc[mt][nt] = __builtin_amdgcn_mfma_f32_16x16x32_bf16(sl, bh[nt], acc[mt][nt], 0, 0, 0);
                acc[mt][nt] = __builtin_amdgcn_mfma_f32_16x16x32_bf16(sh, bl[nt], acc[mt][nt], 0, 0, 0);
            }
        }
    }

    // epilogue in two 32-row passes through LDS; fully coalesced stream
    const float4* xg = (const float4*)(x + pbase * Cc);
    float4* og = (float4*)(out + pbase * Cc);
    const float4 dv = ((const float4*)Dp)[lane];
    #pragma unroll
    for (int hh = 0; hh < 2; ++hh) {
        __syncthreads();                // smem free (S dead / prev pass done)
        #pragma unroll
        for (int mt2 = 0; mt2 < 2; ++mt2) {
            int mt = hh * 2 + mt2;
            #pragma unroll
            for (int nt = 0; nt < 4; ++nt) {
                int c = wv * 64 + nt * 16 + mi;
                #pragma unroll
                for (int reg = 0; reg < 4; ++reg)
                    smem[(mt2 * 16 + q * 4 + reg) * 260 + c] = acc[mt][nt][reg];
            }
        }
        __syncthreads();
        #pragma unroll 4
        for (int i = 0; i < 8; ++i) {
            int fi = i * 256 + t;       // local row = i*4+wv, col4 = lane
            int pl = i * 4 + wv;
            long pg = pbase + hh * 32 + pl;
            float4 vv = *(const float4*)&smem[pl * 260 + lane * 4];
            float m = Mst[pg], s = Sst[pg];
            float4 xv = xg[hh * 2048 + fi];
            og[hh * 2048 + fi] = make_float4(
                vv.x + dv.x * ((xv.x - m) * s),
                vv.y + dv.y * ((xv.y - m) * s),
                vv.z + dv.z * ((xv.z - m) * s),
                vv.w + dv.w * ((xv.w - m) * s));
        }
    }
}

extern "C" void kernel_launch(void* const* d_in, const int* in_sizes, int n_in,
                              void* d_out, int out_size, void* d_ws, size_t ws_size,
                              hipStream_t stream)
{
    const float* x    = (const float*)d_in[0];
    const float* snr  = (const float*)d_in[1];
    const float* A    = (const float*)d_in[2];
    const float* Bp   = (const float*)d_in[3];
    const float* Cp   = (const float*)d_in[4];
    const float* Dp   = (const float*)d_in[5];
    const float* Win  = (const float*)d_in[6];
    const float* Wout = (const float*)d_in[7];
    float* out = (float*)d_out;

    char* ws = (char*)d_ws;
    float*  Bu   = (float*)(ws);                                        // 8 MiB
    float*  Srow = (float*)(ws + (size_t)8  * 1024 * 1024);             // 8 MiB
    float*  Scol = (float*)(ws + (size_t)16 * 1024 * 1024);             // 8 MiB
    float*  E    = (float*)(ws + (size_t)24 * 1024 * 1024);             // 512 KiB
    float*  Pf   = (float*)(ws + (size_t)24 * 1024 * 1024 + 512*1024);  // 256 KiB
    float*  Pb   = (float*)(ws + (size_t)24 * 1024 * 1024 + 768*1024);  // 256 KiB
    float*  Mst  = (float*)(ws + (size_t)25 * 1024 * 1024);             // 128 KiB
    float*  Sst  = (float*)(ws + (size_t)25 * 1024 * 1024 + 128*1024);  // 128 KiB
    char*   wbase = ws + (size_t)25 * 1024 * 1024 + 512 * 1024;
    __bf16* Wh   = (__bf16*)(wbase);                                    // 32 KiB
    __bf16* Wl   = (__bf16*)(wbase + 32 * 1024);                        // 32 KiB
    __bf16* Woh  = (__bf16*)(wbase + 64 * 1024);                        // 32 KiB
    __bf16* Wol  = (__bf16*)(wbase + 96 * 1024);                        // 32 KiB
    float*  WB   = (float*)(wbase + 128 * 1024);                        // 256 B

    hipLaunchKernelGGL(k0_weights,  dim3(9),   dim3(256), 0, stream, Win, Wout, Bp, Cp, Wh, Wl, Woh, Wol, WB);
    hipLaunchKernelGGL(k1_ln_gemm,  dim3(512), dim3(256), 0, stream, x, Wh, Wl, Bp, WB, Bu, Mst, Sst);
    hipLaunchKernelGGL(k2_carry,    dim3(512), dim3(256), 0, stream, Bu, A, snr, E, Pf, Pb);
    hipLaunchKernelGGL(k4_apply,    dim3(512), dim3(256), 0, stream, Bu, E, Pf, Pb, A, snr, Srow, Scol);
    hipLaunchKernelGGL(k5_gemm_out, dim3(512), dim3(256), 0, stream, Srow, Scol, x, Woh, Wol, Dp, Mst, Sst, out);
}

// Round 9
// 142.456 us; speedup vs baseline: 1.0957x; 1.0957x over previous
//
#include <hip/hip_runtime.h>
#include <hip/hip_bf16.h>
#include <math.h>

#define Bsz 8
#define Hh 64
#define Ww 64
#define Cc 256
#define Nn 64
#define Ll 4096      /* Hh*Ww */
#define EPSf 1e-5f

typedef __bf16 v8bf __attribute__((ext_vector_type(8)));
typedef float  f32x4 __attribute__((ext_vector_type(4)));

__device__ __forceinline__ float ad_val(float a, float snr) {
    float s = fminf(fmaxf(snr, 0.f), 1.f);
    float scale = 0.6f + 0.4f * s;
    float v = tanhf(a) * scale;
    return fminf(fmaxf(v, -0.99f), 0.99f);
}

// K0: weights -> bf16 MFMA B-fragment order. W_in and Wo' (= Wout*0.25*Cp[k])
// stored as hi/lo bf16 splits. WB = rowsum(Win)*Bp. (R7-proven.)
__global__ __launch_bounds__(256) void k0_weights(
    const float* __restrict__ Win, const float* __restrict__ Wout,
    const float* __restrict__ Bp, const float* __restrict__ Cp,
    __bf16* __restrict__ Wh, __bf16* __restrict__ Wl,
    __bf16* __restrict__ Woh, __bf16* __restrict__ Wol,
    float* __restrict__ WB)
{
    const int t = threadIdx.x;
    const int blk = blockIdx.x;
    if (blk < 4) {
        for (int idx = blk * 512 + t; idx < blk * 512 + 512; idx += 256) {
            int tile = idx >> 6, lane = idx & 63;
            int kt = tile >> 2, nt = tile & 3;
            int q = lane >> 4, n = nt * 16 + (lane & 15);
            #pragma unroll
            for (int j = 0; j < 8; ++j) {
                int k = kt * 32 + q * 8 + j;
                float w = Win[n * Cc + k];
                __bf16 h = (__bf16)w;
                Wh[idx * 8 + j] = h;
                Wl[idx * 8 + j] = (__bf16)(w - (float)h);
            }
        }
    } else if (blk < 8) {
        for (int idx = (blk - 4) * 512 + t; idx < (blk - 4) * 512 + 512; idx += 256) {
            int tile = idx >> 6, lane = idx & 63;
            int kt = tile >> 4, ntg = tile & 15;
            int q = lane >> 4, c = ntg * 16 + (lane & 15);
            #pragma unroll
            for (int j = 0; j < 8; ++j) {
                int k = kt * 32 + q * 8 + j;
                float w = Wout[c * Nn + k] * 0.25f * Cp[k];
                __bf16 h = (__bf16)w;
                Woh[idx * 8 + j] = h;
                Wol[idx * 8 + j] = (__bf16)(w - (float)h);
            }
        }
    } else {
        __shared__ float wtmp[256];
        int n = t >> 2, qd = t & 3;
        float s = 0.f;
        const float* wr = Win + (long)n * Cc + qd * 64;
        for (int i = 0; i < 64; ++i) s += wr[i];
        wtmp[t] = s;
        __syncthreads();
        if (t < 64)
            WB[t] = (wtmp[t*4] + wtmp[t*4+1] + wtmp[t*4+2] + wtmp[t*4+3]) * Bp[t];
    }
}

// K1: LN stats + MFMA input projection + ROW chunk carries.
// Block = one row chunk (b = blk>>6, h=j = blk&63). Bu tile staged in LDS
// (coalesced store), then quarter-partial row carries (Ad^16 composition,
// accuracy-proven by R8) -> E dirs 0,1. 512 blocks x 256 thr.
__global__ __launch_bounds__(256) void k1_ln_gemm(
    const float* __restrict__ x, const __bf16* __restrict__ Wh,
    const __bf16* __restrict__ Wl, const float* __restrict__ Bp,
    const float* __restrict__ WB, const float* __restrict__ A,
    const float* __restrict__ snr, float* __restrict__ Bu,
    float* __restrict__ E, float* __restrict__ Mst, float* __restrict__ Sst)
{
    __shared__ float zs[64 * 68];
    __shared__ float exch[8 * 64];
    __shared__ float mrow[64], srow[64];
    const int t = threadIdx.x;
    const int lane = t & 63;
    const int wv = __builtin_amdgcn_readfirstlane(t >> 6);
    const long pbase = (long)blockIdx.x * 64;
    const int b = blockIdx.x >> 6;
    const int j = blockIdx.x & 63;
    const float* xt = x + pbase * Cc;

    for (int rr = 0; rr < 16; ++rr) {
        int r = wv * 16 + rr;
        float4 v = ((const float4*)(xt + (long)r * Cc))[lane];
        float s = v.x + v.y + v.z + v.w;
        float qq = v.x*v.x + v.y*v.y + v.z*v.z + v.w*v.w;
        #pragma unroll
        for (int off = 32; off > 0; off >>= 1) {
            s += __shfl_down(s, off);
            qq += __shfl_down(qq, off);
        }
        if (lane == 0) {
            float m = s * (1.f/256.f);
            float var = fmaxf(qq * (1.f/256.f) - m*m, 0.f);
            float r1 = rsqrtf(var + EPSf);
            float v2 = var / (var + EPSf);
            float sc = r1 * rsqrtf(v2 + EPSf);
            mrow[r] = m; srow[r] = sc;
            Mst[pbase + r] = m; Sst[pbase + r] = sc;
        }
    }
    __syncthreads();

    const int q = lane >> 4;
    const int mi = lane & 15;
    const float* xa = xt + (long)(wv * 16 + mi) * Cc + q * 8;

    f32x4 acc[4];
    #pragma unroll
    for (int nt = 0; nt < 4; ++nt) acc[nt] = (f32x4){0.f, 0.f, 0.f, 0.f};

    #pragma unroll
    for (int kt = 0; kt < 8; ++kt) {
        float4 a0 = *(const float4*)(xa + kt * 32);
        float4 a1 = *(const float4*)(xa + kt * 32 + 4);
        float av[8] = {a0.x, a0.y, a0.z, a0.w, a1.x, a1.y, a1.z, a1.w};
        v8bf ah, al;
        #pragma unroll
        for (int jj = 0; jj < 8; ++jj) {
            __bf16 h = (__bf16)av[jj];
            ah[jj] = h;
            al[jj] = (__bf16)(av[jj] - (float)h);
        }
        #pragma unroll
        for (int nt = 0; nt < 4; ++nt) {
            v8bf bh = *(const v8bf*)(Wh + ((long)(kt * 4 + nt) * 64 + lane) * 8);
            v8bf bl = *(const v8bf*)(Wl + ((long)(kt * 4 + nt) * 64 + lane) * 8);
            acc[nt] = __builtin_amdgcn_mfma_f32_16x16x32_bf16(ah, bh, acc[nt], 0, 0, 0);
            acc[nt] = __builtin_amdgcn_mfma_f32_16x16x32_bf16(al, bh, acc[nt], 0, 0, 0);
            acc[nt] = __builtin_amdgcn_mfma_f32_16x16x32_bf16(ah, bl, acc[nt], 0, 0, 0);
        }
    }

    // epilogue values -> LDS tile [pos][n] stride 68
    #pragma unroll
    for (int nt = 0; nt < 4; ++nt) {
        int n = nt * 16 + mi;
        float bpn = Bp[n];
        float wbn = WB[n];
        #pragma unroll
        for (int reg = 0; reg < 4; ++reg) {
            int p = wv * 16 + q * 4 + reg;
            float m = mrow[p], s = srow[p];
            zs[p * 68 + n] = s * (acc[nt][reg] * bpn - m * wbn);
        }
    }
    __syncthreads();
    // coalesced Bu store
    float4* bug = (float4*)(Bu + pbase * Nn);
    #pragma unroll
    for (int i = 0; i < 4; ++i) {
        int fi = i * 256 + t;
        bug[fi] = *(const float4*)&zs[(fi >> 4) * 68 + (fi & 15) * 4];
    }
    // row-direction chunk carries: lane = n, wave = position quarter
    const float Ad = ad_val(A[lane], snr[b]);
    float v[16];
    #pragma unroll
    for (int k = 0; k < 16; ++k) v[k] = zs[(wv * 16 + k) * 68 + lane];
    float pf = 0.f, pb = 0.f;
    #pragma unroll
    for (int k = 0; k < 16; ++k) pf = fmaf(Ad, pf, v[k]);
    #pragma unroll
    for (int k = 15; k >= 0; --k) pb = fmaf(Ad, pb, v[k]);
    exch[wv * 64 + lane] = pf;
    exch[(4 + wv) * 64 + lane] = pb;
    __syncthreads();
    if (t < 64) {
        float p16 = Ad;
        #pragma unroll
        for (int i = 0; i < 4; ++i) p16 *= p16;   // Ad^16
        float ef = exch[lane];
        ef = fmaf(p16, ef, exch[64 + lane]);
        ef = fmaf(p16, ef, exch[128 + lane]);
        ef = fmaf(p16, ef, exch[192 + lane]);
        E[((0 * 8 + b) * 64 + j) * 64 + lane] = ef;
        float eb = exch[(4 + 3) * 64 + lane];
        eb = fmaf(p16, eb, exch[(4 + 2) * 64 + lane]);
        eb = fmaf(p16, eb, exch[(4 + 1) * 64 + lane]);
        eb = fmaf(p16, eb, exch[(4 + 0) * 64 + lane]);
        E[((1 * 8 + b) * 64 + (63 - j)) * 64 + lane] = eb;
    }
}

// K2c: COLUMN chunk carries only (R7-proven full-64 chains, no reconstruction).
// 128 blocks x 256 thr; 512 tasks (b, w=j). Writes E dirs 2,3.
__global__ __launch_bounds__(256) void k2_col(
    const float* __restrict__ Bu, const float* __restrict__ A,
    const float* __restrict__ snr, float* __restrict__ E)
{
    const int t = threadIdx.x;
    const int lane = t & 63;
    const int task = blockIdx.x * 4 + (t >> 6);    // 0..511
    const int b = (task >> 6) & 7;
    const int j = task & 63;
    const float Ad = ad_val(A[lane], snr[b]);
    const float* src = Bu + ((long)b * Ll + j) * Nn + lane;
    const long stride = (long)Ww * Nn;

    float v[64];
    #pragma unroll
    for (int k = 0; k < 64; ++k) v[k] = src[k * stride];

    float s = 0.f;
    #pragma unroll
    for (int k = 0; k < 64; ++k) s = fmaf(Ad, s, v[k]);
    E[((2 * 8 + b) * 64 + j) * 64 + lane] = s;

    float sb = 0.f;
    #pragma unroll
    for (int k = 63; k >= 0; --k) sb = fmaf(Ad, sb, v[k]);
    E[((3 * 8 + b) * 64 + (63 - j)) * 64 + lane] = sb;
}

// K3: per-sequence carry prefix (exclusive scan, Ad^64 composition).
// 32 blocks (dir*8+b) x 64 thr. (R7-proven; DO NOT inline into k4 — R8 lesson.)
__global__ __launch_bounds__(64) void k3_prefix(
    const float* __restrict__ E, float* __restrict__ CT,
    const float* __restrict__ A, const float* __restrict__ snr)
{
    const int lane = threadIdx.x;
    const int db = blockIdx.x;
    const int b = db & 7;
    float Ad = ad_val(A[lane], snr[b]);
    float p64 = Ad;
    #pragma unroll
    for (int i = 0; i < 6; ++i) p64 *= p64;        // Ad^64
    const float* e = E + (long)db * 4096 + lane;
    float* ct = CT + (long)db * 4096 + lane;
    float v[64];
    #pragma unroll
    for (int k = 0; k < 64; ++k) v[k] = e[k * 64];
    float c = 0.f;
    #pragma unroll
    for (int k = 0; k < 64; ++k) {
        ct[k * 64] = c;
        c = fmaf(p64, c, v[k]);
    }
}

// K4c: COLUMN apply only (R7-proven seeded chains, no reconstruction).
// 128 blocks x 256 thr; 512 tasks. Writes Scol (fp32).
__global__ __launch_bounds__(256) void k4_col(
    const float* __restrict__ Bu, const float* __restrict__ CT,
    const float* __restrict__ A, const float* __restrict__ snr,
    float* __restrict__ Scol)
{
    const int t = threadIdx.x;
    const int lane = t & 63;
    const int task = blockIdx.x * 4 + (t >> 6);    // 0..511
    const int b = (task >> 6) & 7;
    const int j = task & 63;
    const float Ad = ad_val(A[lane], snr[b]);
    const float* src = Bu + ((long)b * Ll + j) * Nn + lane;
    const long stride = (long)Ww * Nn;
    const float cf = CT[((2 * 8 + b) * 64 + j) * 64 + lane];
    const float cb = CT[((3 * 8 + b) * 64 + (63 - j)) * 64 + lane];

    float v[64];
    #pragma unroll
    for (int k = 0; k < 64; ++k) v[k] = src[k * stride];

    float hf[64];
    float h = cf;
    #pragma unroll
    for (int k = 0; k < 64; ++k) { h = fmaf(Ad, h, v[k]); hf[k] = h; }

    float* out0 = Scol + ((long)b * Ll + j) * Nn + lane;
    float sb = cb;
    #pragma unroll
    for (int k = 63; k >= 0; --k) {
        sb = fmaf(Ad, sb, v[k]);
        out0[k * stride] = hf[k] + sb;
    }
}

// K5: fused ROW apply + output GEMM + epilogue. Block = one row chunk.
// Stage Bu tile -> two-level seeded row scans in regs (Ad^16 composition)
// -> S_row into LDS -> += Scol -> 3-term bf16 split GEMM (Wo'=0.25*Cp folded)
// -> two-pass LDS epilogue (R8 pattern). 512 blocks x 256 thr, ~35 KB LDS.
__global__ __launch_bounds__(256) void k5_fused(
    const float* __restrict__ Bu, const float* __restrict__ Scol,
    const float* __restrict__ CT, const float* __restrict__ x,
    const __bf16* __restrict__ Woh, const __bf16* __restrict__ Wol,
    const float* __restrict__ A, const float* __restrict__ snr,
    const float* __restrict__ Dp, const float* __restrict__ Mst,
    const float* __restrict__ Sst, float* __restrict__ out)
{
    __shared__ float smem[8320];        // Bu/S tile (stride 68) then out tile (260)
    __shared__ float exch[8 * 64];
    const int t = threadIdx.x;
    const int lane = t & 63;
    const int wv = __builtin_amdgcn_readfirstlane(t >> 6);
    const int b = blockIdx.x >> 6;
    const int j = blockIdx.x & 63;
    const long pbase = (long)blockIdx.x * 64;
    const int q = lane >> 4;
    const int mi = lane & 15;

    // stage Bu chunk tile [64 pos x 64 n], stride 68
    const float4* Bg = (const float4*)(Bu + pbase * Nn);
    #pragma unroll
    for (int i = 0; i < 4; ++i) {
        int fi = i * 256 + t;
        *(float4*)&smem[(fi >> 4) * 68 + (fi & 15) * 4] = Bg[fi];
    }
    __syncthreads();

    // seeded row scans: lane = n, wave = position quarter
    const float Ad = ad_val(A[lane], snr[b]);
    float p16 = Ad;
    #pragma unroll
    for (int i = 0; i < 4; ++i) p16 *= p16;        // Ad^16
    float v[16];
    #pragma unroll
    for (int k = 0; k < 16; ++k) v[k] = smem[(wv * 16 + k) * 68 + lane];
    float pf = 0.f, pb = 0.f;
    #pragma unroll
    for (int k = 0; k < 16; ++k) pf = fmaf(Ad, pf, v[k]);
    #pragma unroll
    for (int k = 15; k >= 0; --k) pb = fmaf(Ad, pb, v[k]);
    exch[wv * 64 + lane] = pf;
    exch[(4 + wv) * 64 + lane] = pb;
    const float cf = CT[((0 * 8 + b) * 64 + j) * 64 + lane];
    const float cb = CT[((1 * 8 + b) * 64 + (63 - j)) * 64 + lane];
    __syncthreads();
    float cw = cf;                                  // carry entering quarter wv
    for (int wq = 0; wq < wv; ++wq) cw = fmaf(p16, cw, exch[wq * 64 + lane]);
    float dw = cb;                                  // bwd carry entering from right
    for (int wq = 3; wq > wv; --wq) dw = fmaf(p16, dw, exch[(4 + wq) * 64 + lane]);

    float hf[16];
    float h = cw;
    #pragma unroll
    for (int k = 0; k < 16; ++k) { h = fmaf(Ad, h, v[k]); hf[k] = h; }
    float sb = dw;
    #pragma unroll
    for (int k = 15; k >= 0; --k) {
        sb = fmaf(Ad, sb, v[k]);
        smem[(wv * 16 + k) * 68 + lane] = hf[k] + sb;   // S_row (overwrites Bu)
    }
    __syncthreads();

    // += Scol (coalesced float4 RMW)
    const float4* Sc = (const float4*)(Scol + pbase * Nn);
    #pragma unroll
    for (int i = 0; i < 4; ++i) {
        int fi = i * 256 + t;
        float* d = &smem[(fi >> 4) * 68 + (fi & 15) * 4];
        float4 c = Sc[fi];
        float4 cur = *(const float4*)d;
        *(float4*)d = make_float4(cur.x + c.x, cur.y + c.y, cur.z + c.z, cur.w + c.w);
    }
    __syncthreads();

    // 3-term bf16 split GEMM (R7-proven)
    f32x4 acc[4][4];
    #pragma unroll
    for (int mt = 0; mt < 4; ++mt)
        #pragma unroll
        for (int nt = 0; nt < 4; ++nt) acc[mt][nt] = (f32x4){0.f, 0.f, 0.f, 0.f};

    #pragma unroll
    for (int kt = 0; kt < 2; ++kt) {
        v8bf bh[4], bl[4];
        #pragma unroll
        for (int nt = 0; nt < 4; ++nt) {
            long wo = ((long)(kt * 16 + wv * 4 + nt) * 64 + lane) * 8;
            bh[nt] = *(const v8bf*)(Woh + wo);
            bl[nt] = *(const v8bf*)(Wol + wo);
        }
        #pragma unroll
        for (int mt = 0; mt < 4; ++mt) {
            const float* ar = &smem[(mt * 16 + mi) * 68 + q * 8 + kt * 32];
            v8bf sh, sl;
            #pragma unroll
            for (int jj = 0; jj < 8; ++jj) {
                float sv = ar[jj];
                __bf16 hh = (__bf16)sv;
                sh[jj] = hh;
                sl[jj] = (__bf16)(sv - (float)hh);
            }
            #pragma unroll
            for (int nt = 0; nt < 4; ++nt) {
                acc[mt][nt] = __builtin_amdgcn_mfma_f32_16x16x32_bf16(sh, bh[nt], acc[mt][nt], 0, 0, 0);
                acc[mt][nt] = __builtin_amdgcn_mfma_f32_16x16x32_bf16(sl, bh[nt], acc[mt][nt], 0, 0, 0);
                acc[mt][nt] = __builtin_amdgcn_mfma_f32_16x16x32_bf16(sh, bl[nt], acc[mt][nt], 0, 0, 0);
            }
        }
    }

    // epilogue in two 32-row passes through LDS (R8 pattern)
    const float4* xg = (const float4*)(x + pbase * Cc);
    float4* og = (float4*)(out + pbase * Cc);
    const float4 dv = ((const float4*)Dp)[lane];
    #pragma unroll
    for (int hh = 0; hh < 2; ++hh) {
        __syncthreads();                // S tile dead / prev pass done
        #pragma unroll
        for (int mt2 = 0; mt2 < 2; ++mt2) {
            int mt = hh * 2 + mt2;
            #pragma unroll
            for (int nt = 0; nt < 4; ++nt) {
                int c = wv * 64 + nt * 16 + mi;
                #pragma unroll
                for (int reg = 0; reg < 4; ++reg)
                    smem[(mt2 * 16 + q * 4 + reg) * 260 + c] = acc[mt][nt][reg];
            }
        }
        __syncthreads();
        #pragma unroll 4
        for (int i = 0; i < 8; ++i) {
            int fi = i * 256 + t;       // local row = i*4+wv (uniform), col4 = lane
            int pl = i * 4 + wv;
            long pg = pbase + hh * 32 + pl;
            float4 vv = *(const float4*)&smem[pl * 260 + lane * 4];
            float m = Mst[pg], s = Sst[pg];
            float4 xv = xg[hh * 2048 + fi];
            og[hh * 2048 + fi] = make_float4(
                vv.x + dv.x * ((xv.x - m) * s),
                vv.y + dv.y * ((xv.y - m) * s),
                vv.z + dv.z * ((xv.z - m) * s),
                vv.w + dv.w * ((xv.w - m) * s));
        }
    }
}

extern "C" void kernel_launch(void* const* d_in, const int* in_sizes, int n_in,
                              void* d_out, int out_size, void* d_ws, size_t ws_size,
                              hipStream_t stream)
{
    const float* x    = (const float*)d_in[0];
    const float* snr  = (const float*)d_in[1];
    const float* A    = (const float*)d_in[2];
    const float* Bp   = (const float*)d_in[3];
    const float* Cp   = (const float*)d_in[4];
    const float* Dp   = (const float*)d_in[5];
    const float* Win  = (const float*)d_in[6];
    const float* Wout = (const float*)d_in[7];
    float* out = (float*)d_out;

    char* ws = (char*)d_ws;
    float*  Bu   = (float*)(ws);                                        // 8 MiB
    float*  Scol = (float*)(ws + (size_t)8  * 1024 * 1024);             // 8 MiB
    float*  E    = (float*)(ws + (size_t)16 * 1024 * 1024);             // 512 KiB
    float*  CT   = (float*)(ws + (size_t)16 * 1024 * 1024 + 512*1024);  // 512 KiB
    float*  Mst  = (float*)(ws + (size_t)17 * 1024 * 1024);             // 128 KiB
    float*  Sst  = (float*)(ws + (size_t)17 * 1024 * 1024 + 128*1024);  // 128 KiB
    char*   wbase = ws + (size_t)18 * 1024 * 1024;
    __bf16* Wh   = (__bf16*)(wbase);                                    // 32 KiB
    __bf16* Wl   = (__bf16*)(wbase + 32 * 1024);                        // 32 KiB
    __bf16* Woh  = (__bf16*)(wbase + 64 * 1024);                        // 32 KiB
    __bf16* Wol  = (__bf16*)(wbase + 96 * 1024);                        // 32 KiB
    float*  WB   = (float*)(wbase + 128 * 1024);                        // 256 B

    hipLaunchKernelGGL(k0_weights, dim3(9),   dim3(256), 0, stream, Win, Wout, Bp, Cp, Wh, Wl, Woh, Wol, WB);
    hipLaunchKernelGGL(k1_ln_gemm, dim3(512), dim3(256), 0, stream, x, Wh, Wl, Bp, WB, A, snr, Bu, E, Mst, Sst);
    hipLaunchKernelGGL(k2_col,     dim3(128), dim3(256), 0, stream, Bu, A, snr, E);
    hipLaunchKernelGGL(k3_prefix,  dim3(32),  dim3(64),  0, stream, E, CT, A, snr);
    hipLaunchKernelGGL(k4_col,     dim3(128), dim3(256), 0, stream, Bu, CT, A, snr, Scol);
    hipLaunchKernelGGL(k5_fused,   dim3(512), dim3(256), 0, stream, Bu, Scol, CT, x, Woh, Wol, A, snr, Dp, Mst, Sst, out);
}